// Round 3
// baseline (1377.219 us; speedup 1.0000x reference)
//
#include <hip/hip_runtime.h>
#include <cstdint>

// Problem dims (fixed by reference): B=4, S=2048 -> M=8192, K=4096, N=16384
#define MDIM 8192
#define KDIM 4096
#define NDIM 16384

// GEMM geometry: 256x256 tile, 512 thr / 8 waves (2M x 4N), BK=64 bytes,
// 4-deep global_load_lds pipeline with counted vmcnt (T3+T4), T2 swizzle,
// T5 setprio, T1 XCD-chunked block swizzle.
// Round 3: DISTINCT LDS OBJECTS per pipeline buffer (a0..a3, b0..b3).
// SIInsertWaitcnts tracks LDS-DMA aliasing per memory OBJECT; with one
// lds_a[4][...] array every ds_read waited on the newest in-flight prefetch
// (hidden per-phase drain). Separate objects let the pass disambiguate.
#define BM 256
#define BN 256
#define BKB 64              // K-bytes per tile step (1 mfma k-step)
#define NT (KDIM / BKB)     // 64 K-tiles

typedef int v4i __attribute__((ext_vector_type(4)));

__device__ __forceinline__ void gload_lds16(const void* g, void* l) {
    __builtin_amdgcn_global_load_lds(
        (const __attribute__((address_space(1))) int*)g,
        (__attribute__((address_space(3))) int*)l, 16, 0, 0);
}

// ---------------------------------------------------------------------------
// Kernel 1: pack W int32 [N,K] -> int8 [N,K]. One int4 (4 ints) -> one int (4 bytes).
__global__ __launch_bounds__(256) void conv_w(const int4* __restrict__ w,
                                              int* __restrict__ wq) {
    int g = blockIdx.x * 256 + threadIdx.x;   // int4 index; total N*K/4 = 16777216
    int4 v = w[g];
    unsigned p = (unsigned)(v.x & 255) | ((unsigned)(v.y & 255) << 8) |
                 ((unsigned)(v.z & 255) << 16) | ((unsigned)(v.w & 255) << 24);
    wq[g] = (int)p;
}

// ---------------------------------------------------------------------------
// Kernel 2: per-row absmax quantize of x [M,K] fp32 -> int8 + scale_x[M].
__global__ __launch_bounds__(256) void quant_rows(const float* __restrict__ x,
                                                  int* __restrict__ xq32,
                                                  float* __restrict__ sx) {
    const int row = blockIdx.x;
    const int t = threadIdx.x;
    const float4* xr = (const float4*)(x + (size_t)row * KDIM);

    float4 v[4];
    float amax = 0.f;
#pragma unroll
    for (int p = 0; p < 4; ++p) {
        v[p] = xr[p * 256 + t];
        amax = fmaxf(amax, fmaxf(fmaxf(fabsf(v[p].x), fabsf(v[p].y)),
                                 fmaxf(fabsf(v[p].z), fabsf(v[p].w))));
    }
#pragma unroll
    for (int off = 32; off > 0; off >>= 1)
        amax = fmaxf(amax, __shfl_down(amax, off));
    __shared__ float wmax[4];
    int wave = t >> 6, lane = t & 63;
    if (lane == 0) wmax[wave] = amax;
    __syncthreads();
    float m = fmaxf(fmaxf(wmax[0], wmax[1]), fmaxf(wmax[2], wmax[3]));

    float inv = (m > 0.f) ? 127.f / m : 0.f;
    if (t == 0) {
        float s = m / 127.f;
        sx[row] = (s == 0.f) ? 1.f : s;
    }

    int* out = xq32 + (size_t)row * (KDIM / 4);
#pragma unroll
    for (int p = 0; p < 4; ++p) {
        int q0 = (int)rintf(v[p].x * inv); q0 = max(-127, min(127, q0));
        int q1 = (int)rintf(v[p].y * inv); q1 = max(-127, min(127, q1));
        int q2 = (int)rintf(v[p].z * inv); q2 = max(-127, min(127, q2));
        int q3 = (int)rintf(v[p].w * inv); q3 = max(-127, min(127, q3));
        unsigned pk = (unsigned)(q0 & 255) | ((unsigned)(q1 & 255) << 8) |
                      ((unsigned)(q2 & 255) << 16) | ((unsigned)(q3 & 255) << 24);
        out[p * 256 + t] = (int)pk;
    }
}

// ---------------------------------------------------------------------------
// Kernel 3: int8 GEMM 256x256 tile; pipeline over 8 distinct LDS buffers.
__global__ __launch_bounds__(512, 2) void gemm_i8(const signed char* __restrict__ xq,
                                                  const signed char* __restrict__ wq,
                                                  const float* __restrict__ sx,
                                                  const float* __restrict__ scale,
                                                  const float* __restrict__ bias,
                                                  float* __restrict__ y) {
    // 8 distinct objects, 16 KiB each = 128 KiB -> 1 block/CU, 2 waves/SIMD
    __shared__ __align__(16) signed char a0_[BM * BKB], a1_[BM * BKB],
                                         a2_[BM * BKB], a3_[BM * BKB];
    __shared__ __align__(16) signed char b0_[BN * BKB], b1_[BN * BKB],
                                         b2_[BN * BKB], b3_[BN * BKB];

    const int tid  = threadIdx.x;
    const int lane = tid & 63;
    const int wave = tid >> 6;           // 0..7
    const int l16  = lane & 15;
    const int quad = lane >> 4;
    const int wm   = wave >> 2;          // 0..1  M-half
    const int wn   = wave & 3;           // 0..3  N-quarter

    // T1: bijective XCD-chunked swizzle (2048 blocks, 2048 % 8 == 0)
    int lin = blockIdx.y * gridDim.x + blockIdx.x;
    lin = (lin & 7) * ((MDIM / BM) * (NDIM / BN) / 8) + (lin >> 3);
    const int tileN = (lin & (NDIM / BN - 1)) * BN;   // lin % 64
    const int tileM = (lin >> 6) * BM;                // lin / 64

    // ---- staging addressing. T2 swizzle: LDS stays LINEAR for global_load_lds;
    // the global SOURCE column is pre-swizzled with the same involution the
    // ds_read side applies (rule 21: both-sides-or-neither).
    const int srow = tid >> 2;                                   // 0..127
    const int scol = ((tid & 3) << 4) ^ (((srow >> 1) & 3) << 4);
    const signed char* gA0 = xq + (size_t)(tileM + srow) * KDIM + scol;
    const signed char* gA1 = gA0 + (size_t)128 * KDIM;           // rows 128..255
    const signed char* gB0 = wq + (size_t)(tileN + srow) * KDIM + scol;
    const signed char* gB1 = gB0 + (size_t)128 * KDIM;
    const int lo = tid << 4;             // linear LDS byte offset of this thread's chunk

    // ---- ds_read addressing with the same XOR swizzle.
    // row = 16*a + l16 -> ((row>>1)&3) == ((l16>>1)&3): per-lane constant.
    const int rcol = (quad << 4) ^ (((l16 >> 1) & 3) << 4);
    const int aoff = (wm * 128 + l16) * BKB + rcol;   // + mf*1024
    const int boff = (wn * 64 + l16) * BKB + rcol;    // + nf*1024

    v4i acc[8][4] = {};

// Stage one A (or B) tile at global byte offset GOFF into named LDS buffer.
#define STAGE_A(GOFF, DST_) do {                                              \
        gload_lds16(gA0 + (GOFF), DST_ + lo);                                 \
        gload_lds16(gA1 + (GOFF), DST_ + lo + 8192); } while (0)
#define STAGE_B(GOFF, DST_) do {                                              \
        gload_lds16(gB0 + (GOFF), DST_ + lo);                                 \
        gload_lds16(gB1 + (GOFF), DST_ + lo + 8192); } while (0)

// One K-tile: reads named buffers LA_/LB_; optionally prefetches the tile at
// global byte offset PFOFF_ into named buffers PA_/PB_.
#define KTILE(LA_, LB_, DO_PF_, PA_, PB_, PFOFF_) do {                        \
    v4i af_[4], bf_[4], ag_[4];                                               \
    _Pragma("unroll")                                                         \
    for (int i_ = 0; i_ < 4; ++i_)                                            \
        af_[i_] = *(const v4i*)(LA_ + aoff + i_ * 1024);                      \
    _Pragma("unroll")                                                         \
    for (int j_ = 0; j_ < 4; ++j_)                                            \
        bf_[j_] = *(const v4i*)(LB_ + boff + j_ * 1024);                      \
    if (DO_PF_) STAGE_A(PFOFF_, PA_);                                         \
    __builtin_amdgcn_s_barrier();                                             \
    asm volatile("s_waitcnt lgkmcnt(0)" ::: "memory");                        \
    __builtin_amdgcn_sched_barrier(0);                                        \
    __builtin_amdgcn_s_setprio(1);                                            \
    _Pragma("unroll")                                                         \
    for (int i_ = 0; i_ < 4; ++i_)                                            \
        _Pragma("unroll")                                                     \
        for (int j_ = 0; j_ < 4; ++j_)                                        \
            acc[i_][j_] = __builtin_amdgcn_mfma_i32_16x16x64_i8(              \
                af_[i_], bf_[j_], acc[i_][j_], 0, 0, 0);                      \
    __builtin_amdgcn_s_setprio(0);                                            \
    __builtin_amdgcn_s_barrier();                                             \
    _Pragma("unroll")                                                         \
    for (int i_ = 0; i_ < 4; ++i_)                                            \
        ag_[i_] = *(const v4i*)(LA_ + aoff + (4 + i_) * 1024);                \
    if (DO_PF_) STAGE_B(PFOFF_, PB_);                                         \
    __builtin_amdgcn_s_barrier();                                             \
    asm volatile("s_waitcnt lgkmcnt(0)" ::: "memory");                        \
    __builtin_amdgcn_sched_barrier(0);                                        \
    __builtin_amdgcn_s_setprio(1);                                            \
    _Pragma("unroll")                                                         \
    for (int i_ = 0; i_ < 4; ++i_)                                            \
        _Pragma("unroll")                                                     \
        for (int j_ = 0; j_ < 4; ++j_)                                        \
            acc[4 + i_][j_] = __builtin_amdgcn_mfma_i32_16x16x64_i8(          \
                ag_[i_], bf_[j_], acc[4 + i_][j_], 0, 0, 0);                  \
    __builtin_amdgcn_s_setprio(0);                                            \
} while (0)

#define VMW(N) asm volatile("s_waitcnt vmcnt(" #N ")" ::: "memory")

    // ---- prologue: tiles 0,1,2 in flight (12 loads); tile0 ready at vmcnt(8)
    STAGE_A((size_t)0 * BKB, a0_); STAGE_B((size_t)0 * BKB, b0_);
    STAGE_A((size_t)1 * BKB, a1_); STAGE_B((size_t)1 * BKB, b1_);
    STAGE_A((size_t)2 * BKB, a2_); STAGE_B((size_t)2 * BKB, b2_);
    VMW(8);
    __builtin_amdgcn_s_barrier();

    // ---- main loop: tiles 0..59 in groups of 4 (buffer t&3 by name),
    // every tile prefetches tile t+3. T4: counted vmcnt(8) once per K-tile.
    for (int g = 0; g < 15; ++g) {
        const size_t kb = (size_t)g * 4 * BKB;   // global byte offset of tile 4g
        KTILE(a0_, b0_, true, a3_, b3_, kb + (size_t)3 * BKB);
        VMW(8);
        __builtin_amdgcn_s_barrier();
        KTILE(a1_, b1_, true, a0_, b0_, kb + (size_t)4 * BKB);
        VMW(8);
        __builtin_amdgcn_s_barrier();
        KTILE(a2_, b2_, true, a1_, b1_, kb + (size_t)5 * BKB);
        VMW(8);
        __builtin_amdgcn_s_barrier();
        KTILE(a3_, b3_, true, a2_, b2_, kb + (size_t)6 * BKB);
        VMW(8);
        __builtin_amdgcn_s_barrier();
    }

    // ---- tail: tiles 60..63 (buffers 0..3); vmcnt countdown 8 -> 4 -> 0.
    KTILE(a0_, b0_, true, a3_, b3_, (size_t)63 * BKB);  // prefetch tile 63
    VMW(8);
    __builtin_amdgcn_s_barrier();
    KTILE(a1_, b1_, false, a0_, b0_, 0);
    VMW(4);
    __builtin_amdgcn_s_barrier();
    KTILE(a2_, b2_, false, a0_, b0_, 0);
    VMW(0);
    __builtin_amdgcn_s_barrier();
    KTILE(a3_, b3_, false, a0_, b0_, 0);   // last tile: no trailing sync needed

    // ---- epilogue: C/D layout col=l16, row=quad*4+r (shape-determined)
    float sxv[8][4];
#pragma unroll
    for (int i = 0; i < 8; ++i)
#pragma unroll
        for (int r = 0; r < 4; ++r)
            sxv[i][r] = sx[tileM + wm * 128 + i * 16 + quad * 4 + r];

#pragma unroll
    for (int j = 0; j < 4; ++j) {
        const int n = tileN + wn * 64 + j * 16 + l16;
        const float scn = scale[n];
        const float bsn = bias[n];
#pragma unroll
        for (int i = 0; i < 8; ++i) {
            const size_t mrow = (size_t)(tileM + wm * 128 + i * 16 + quad * 4);
#pragma unroll
            for (int r = 0; r < 4; ++r)
                y[(mrow + r) * NDIM + n] = (float)acc[i][j][r] * sxv[i][r] * scn + bsn;
        }
    }
#undef STAGE_A
#undef STAGE_B
#undef KTILE
#undef VMW
}

// ---------------------------------------------------------------------------
extern "C" void kernel_launch(void* const* d_in, const int* in_sizes, int n_in,
                              void* d_out, int out_size, void* d_ws, size_t ws_size,
                              hipStream_t stream) {
    const float* x      = (const float*)d_in[0];   // [4,2048,4096] f32
    const int*   wdat   = (const int*)d_in[1];     // [16384,4096] int32 (int8 range)
    const float* scale  = (const float*)d_in[2];   // [16384,1]
    const float* bias   = (const float*)d_in[3];   // [16384]
    float* y = (float*)d_out;                      // [4,2048,16384] f32

    signed char* wq = (signed char*)d_ws;                       // N*K   = 64 MiB
    signed char* xq = wq + (size_t)NDIM * KDIM;                 // M*K   = 32 MiB
    float*       sx = (float*)(xq + (size_t)MDIM * KDIM);       // M*4   = 32 KiB

    conv_w<<<(NDIM * (size_t)KDIM) / 4 / 256, 256, 0, stream>>>((const int4*)wdat,
                                                                (int*)wq);
    quant_rows<<<MDIM, 256, 0, stream>>>(x, (int*)xq, sx);

    dim3 grid(NDIM / BN, MDIM / BM);   // (64, 32) = 2048 blocks
    gemm_i8<<<grid, 512, 0, stream>>>(xq, wq, sx, scale, bias, y);
}